// Round 8
// baseline (198.107 us; speedup 1.0000x reference)
//
#include <hip/hip_runtime.h>
#include <hip/hip_bf16.h>

#define N_NODES 8192
#define F_IN    512
#define F_OUT   256
#define ALPHA   0.2f
#define CHUNK   32
#define NCHUNK  (N_NODES / CHUNK)   // 256
#define SEG     1024                // seg_sort segment length

// ---------------------------------------------------------------------------
// Kernel 1: h = x @ W   [8192,512] x [512,256] -> [8192,256], f32, tiled.
// ---------------------------------------------------------------------------
__global__ __launch_bounds__(256) void gemm_h(const float* __restrict__ A,
                                              const float* __restrict__ B,
                                              float* __restrict__ C) {
    __shared__ float As[16][68];
    __shared__ float Bs[16][68];
    const int t  = threadIdx.x;
    const int m0 = blockIdx.y * 64;
    const int n0 = blockIdx.x * 64;

    const int arow = t >> 2;
    const int ac4  = (t & 3) * 4;
    const int brow = t >> 4;
    const int bc4  = (t & 15) * 4;
    const int ty = t >> 4;
    const int tx = t & 15;

    float acc[4][4] = {};

    for (int k0 = 0; k0 < F_IN; k0 += 16) {
        float4 av = *(const float4*)(A + (size_t)(m0 + arow) * F_IN + k0 + ac4);
        float4 bv = *(const float4*)(B + (size_t)(k0 + brow) * F_OUT + n0 + bc4);
        __syncthreads();
        As[ac4 + 0][arow] = av.x;
        As[ac4 + 1][arow] = av.y;
        As[ac4 + 2][arow] = av.z;
        As[ac4 + 3][arow] = av.w;
        *(float4*)(&Bs[brow][bc4]) = bv;
        __syncthreads();
        #pragma unroll
        for (int k = 0; k < 16; ++k) {
            const float4 a4 = *(const float4*)(&As[k][ty * 4]);
            const float4 b4 = *(const float4*)(&Bs[k][tx * 4]);
            acc[0][0] += a4.x * b4.x; acc[0][1] += a4.x * b4.y;
            acc[0][2] += a4.x * b4.z; acc[0][3] += a4.x * b4.w;
            acc[1][0] += a4.y * b4.x; acc[1][1] += a4.y * b4.y;
            acc[1][2] += a4.y * b4.z; acc[1][3] += a4.y * b4.w;
            acc[2][0] += a4.z * b4.x; acc[2][1] += a4.z * b4.y;
            acc[2][2] += a4.z * b4.z; acc[2][3] += a4.z * b4.w;
            acc[3][0] += a4.w * b4.x; acc[3][1] += a4.w * b4.y;
            acc[3][2] += a4.w * b4.z; acc[3][3] += a4.w * b4.w;
        }
    }
    #pragma unroll
    for (int r = 0; r < 4; ++r) {
        float4 o = make_float4(acc[r][0], acc[r][1], acc[r][2], acc[r][3]);
        *(float4*)(C + (size_t)(m0 + ty * 4 + r) * F_OUT + n0 + tx * 4) = o;
    }
}

// ---------------------------------------------------------------------------
// Kernel 2: s1[i] = h[i,:].a[0:256],  s2[i] = h[i,:].a[256:512]
// ---------------------------------------------------------------------------
__global__ __launch_bounds__(256) void s12_kernel(const float* __restrict__ h,
                                                  const float* __restrict__ a,
                                                  float* __restrict__ s1,
                                                  float* __restrict__ s2) {
    const int wave = threadIdx.x >> 6;
    const int lane = threadIdx.x & 63;
    const int row  = blockIdx.x * 4 + wave;

    const float4 hv = *(const float4*)(h + (size_t)row * F_OUT + lane * 4);
    const float4 a1 = *(const float4*)(a + lane * 4);
    const float4 a2 = *(const float4*)(a + F_OUT + lane * 4);

    float p1 = hv.x * a1.x + hv.y * a1.y + hv.z * a1.z + hv.w * a1.w;
    float p2 = hv.x * a2.x + hv.y * a2.y + hv.z * a2.z + hv.w * a2.w;
    #pragma unroll
    for (int off = 32; off; off >>= 1) {
        p1 += __shfl_xor(p1, off);
        p2 += __shfl_xor(p2, off);
    }
    if (lane == 0) { s1[row] = p1; s2[row] = p2; }
}

// ---------------------------------------------------------------------------
// Kernel 3a: sort 8 segments of 1024 (val,idx) pairs, each block in LDS.
// ---------------------------------------------------------------------------
__global__ __launch_bounds__(1024) void seg_sort(const float* __restrict__ s2,
                                                 float* __restrict__ v,
                                                 int* __restrict__ p) {
    __shared__ float sv[SEG];
    __shared__ int   sp[SEG];
    const int t    = threadIdx.x;
    const int base = blockIdx.x * SEG;
    sv[t] = s2[base + t];
    sp[t] = base + t;
    __syncthreads();
    for (int k = 2; k <= SEG; k <<= 1) {
        for (int j = k >> 1; j > 0; j >>= 1) {
            const int ixj = t ^ j;
            if (ixj > t) {
                const bool up = ((t & k) == 0);
                const float av = sv[t], bv = sv[ixj];
                if (up ? (av > bv) : (av < bv)) {
                    sv[t] = bv; sv[ixj] = av;
                    const int pa = sp[t]; sp[t] = sp[ixj]; sp[ixj] = pa;
                }
            }
            __syncthreads();
        }
    }
    v[base + t] = sv[t];
    p[base + t] = sp[t];
}

// ---------------------------------------------------------------------------
// Kernel 3b: parallel merge of adjacent sorted runs of length L into 2L.
// ---------------------------------------------------------------------------
__global__ __launch_bounds__(256) void merge_pass(const float* __restrict__ vin,
                                                  const int* __restrict__ pin,
                                                  float* __restrict__ vout,
                                                  int* __restrict__ pout,
                                                  int L) {
    const int gid   = blockIdx.x * 256 + threadIdx.x;   // 0..8191
    const int pair  = gid / (2 * L);
    const int local = gid - pair * 2 * L;
    const int beg   = pair * 2 * L;

    if (local < L) {                       // element of run A
        const int i     = local;
        const float key = vin[beg + i];
        const int  idx  = pin[beg + i];
        const float* Brun = vin + beg + L;
        int lo = 0, hi = L;
        while (lo < hi) {                  // lower_bound: # of B < key
            const int mid = (lo + hi) >> 1;
            if (Brun[mid] < key) lo = mid + 1; else hi = mid;
        }
        vout[beg + i + lo] = key;
        pout[beg + i + lo] = idx;
    } else {                               // element of run B
        const int i     = local - L;
        const float key = vin[beg + L + i];
        const int  idx  = pin[beg + L + i];
        const float* Arun = vin + beg;
        int lo = 0, hi = L;
        while (lo < hi) {                  // upper_bound: # of A <= key
            const int mid = (lo + hi) >> 1;
            if (Arun[mid] <= key) lo = mid + 1; else hi = mid;
        }
        vout[beg + lo + i] = key;
        pout[beg + lo + i] = idx;
    }
}

// ---------------------------------------------------------------------------
// Kernel 4: per-chunk TOTALS: cneg[c][f] = sum_chunk wn_j*h[p_j][f],
//           cpos[c][f] = sum_chunk wp_j*h[p_j][f], czn/czp scalar totals.
// ---------------------------------------------------------------------------
__global__ __launch_bounds__(256) void chunk_sums(const float* __restrict__ h,
                                                  const float* __restrict__ v,
                                                  const int* __restrict__ p,
                                                  float* __restrict__ cneg,
                                                  float* __restrict__ cpos,
                                                  float* __restrict__ czn,
                                                  float* __restrict__ czp) {
    const int c = blockIdx.x;
    const int f = threadIdx.x;
    const float M = v[N_NODES - 1];
    float accN = 0.f, accP = 0.f, zn = 0.f, zp = 0.f;
    #pragma unroll 8
    for (int tt = 0; tt < CHUNK; ++tt) {
        const int j = c * CHUNK + tt;
        const float vj = v[j];
        const int pj   = p[j];
        const float wn = __expf(ALPHA * vj);
        const float wp = __expf(vj - M);
        const float hv = h[(size_t)pj * F_OUT + f];
        accN += wn * hv; accP += wp * hv;
        zn += wn; zp += wp;
    }
    cneg[c * F_OUT + f] = accN;
    cpos[c * F_OUT + f] = accP;
    if (f == 0) { czn[c] = zn; czp[c] = zp; }
}

// ---------------------------------------------------------------------------
// Kernel 5: in-place exclusive scans of chunk totals.
// cneg[c][f] <- sum over chunks < c ; cpos[c][f] <- sum over chunks > c.
// czn[c] <- sum c'<c ; czp[c] <- sum c'>c   (parallel LDS scan, NCHUNK==256)
// ---------------------------------------------------------------------------
__global__ __launch_bounds__(256) void scan_chunks(float* __restrict__ cneg,
                                                   float* __restrict__ cpos,
                                                   float* __restrict__ czn,
                                                   float* __restrict__ czp) {
    const int f = threadIdx.x;
    // vector scans: thread f owns feature column f, serial over 256 chunks
    // (coalesced 1KB load per iteration, independent addresses -> pipelined)
    float run = 0.f;
    #pragma unroll 4
    for (int c = 0; c < NCHUNK; ++c) {
        const float tv = cneg[c * F_OUT + f];
        cneg[c * F_OUT + f] = run;
        run += tv;
    }
    float runp = 0.f;
    #pragma unroll 4
    for (int c = NCHUNK - 1; c >= 0; --c) {
        const float tv = cpos[c * F_OUT + f];
        cpos[c * F_OUT + f] = runp;
        runp += tv;
    }
    // scalar scans: ALL 256 threads, Hillis-Steele in LDS (was thread-0 serial)
    __shared__ float bufn[NCHUNK];
    __shared__ float bufp[NCHUNK];
    const float on = czn[f];
    const float op = czp[f];
    bufn[f] = on;
    bufp[f] = op;
    __syncthreads();
    #pragma unroll
    for (int off = 1; off < NCHUNK; off <<= 1) {
        const float an = (f >= off) ? bufn[f - off] : 0.f;           // prefix dir
        const float ap = (f + off < NCHUNK) ? bufp[f + off] : 0.f;   // suffix dir
        __syncthreads();
        bufn[f] += an;
        bufp[f] += ap;
        __syncthreads();
    }
    czn[f] = bufn[f] - on;   // exclusive prefix
    czp[f] = bufp[f] - op;   // exclusive suffix
}

// ---------------------------------------------------------------------------
// Kernel 6: per-row output, fused tail (replaces fill_prefix + rows).
// For row i: k = lower_bound(v, -s1_i); c = chunk of k.
//   prefN(k) = cnegS[c] + sum_{j=c*32}^{k-1} wn_j h[p_j]   (vector + scalar)
//   sufP(k)  = cposS[c] + sum_{j=k}^{c*32+31} wp_j h[p_j]
// One wave per row (64 lanes x float4 = 256 features), 4 rows/block.
// Tail reads chunk c's 32 h-rows straight from L2 (~32KB/wave).
// ---------------------------------------------------------------------------
__global__ __launch_bounds__(256) void rows2_kernel(const float* __restrict__ s1,
                                                    const float* __restrict__ v,
                                                    const int* __restrict__ p,
                                                    const float* __restrict__ h,
                                                    const float* __restrict__ cnegS,
                                                    const float* __restrict__ cposS,
                                                    const float* __restrict__ cznS,
                                                    const float* __restrict__ czpS,
                                                    float* __restrict__ out) {
    const int wave = threadIdx.x >> 6;
    const int lane = threadIdx.x & 63;
    const int i = blockIdx.x * 4 + wave;

    const float s1v = s1[i];
    const float M   = v[N_NODES - 1];

    // lower_bound: first k with v[k] >= -s1v
    const float thr = -s1v;
    int lo = 0, hi = N_NODES;
    while (lo < hi) {
        const int mid = (lo + hi) >> 1;
        if (v[mid] < thr) lo = mid + 1; else hi = mid;
    }
    const int k = lo;
    const int c = min(k >> 5, NCHUNK - 1);   // k==N maps into last chunk
    const int start = c * CHUNK;

    // bases from chunk-level exclusive scans
    const float4 bN = *(const float4*)(cnegS + (size_t)c * F_OUT + lane * 4);
    const float4 bP = *(const float4*)(cposS + (size_t)c * F_OUT + lane * 4);
    float aN0 = bN.x, aN1 = bN.y, aN2 = bN.z, aN3 = bN.w;
    float aP0 = bP.x, aP1 = bP.y, aP2 = bP.z, aP3 = bP.w;
    float zn = cznS[c];
    float zp = czpS[c];

    // in-wave tail over chunk c (32 rows, each 1KB coalesced across the wave)
    #pragma unroll 8
    for (int tt = 0; tt < CHUNK; ++tt) {
        const int j = start + tt;
        const float vj = v[j];
        const int pj   = p[j];
        const float4 hv = *(const float4*)(h + (size_t)pj * F_OUT + lane * 4);
        if (j < k) {
            const float wn = __expf(ALPHA * vj);
            aN0 += wn * hv.x; aN1 += wn * hv.y; aN2 += wn * hv.z; aN3 += wn * hv.w;
            zn += wn;
        } else {
            const float wp = __expf(vj - M);
            aP0 += wp * hv.x; aP1 += wp * hv.y; aP2 += wp * hv.z; aP3 += wp * hv.w;
            zp += wp;
        }
    }

    const float x  = s1v + M;
    const float m  = (x >= 0.f) ? x : ALPHA * x;   // exact row max of e
    const float cp = __expf(x - m);
    const float cn = __expf(ALPHA * s1v - m);

    const float invZ = 1.0f / (cp * zp + cn * zn);

    float4 o;
    o.x = (cp * aP0 + cn * aN0) * invZ;
    o.y = (cp * aP1 + cn * aN1) * invZ;
    o.z = (cp * aP2 + cn * aN2) * invZ;
    o.w = (cp * aP3 + cn * aN3) * invZ;
    o.x = (o.x > 0.f) ? o.x : expm1f(o.x);
    o.y = (o.y > 0.f) ? o.y : expm1f(o.y);
    o.z = (o.z > 0.f) ? o.z : expm1f(o.z);
    o.w = (o.w > 0.f) ? o.w : expm1f(o.w);
    *(float4*)(out + (size_t)i * F_OUT + lane * 4) = o;
}

// ---------------------------------------------------------------------------
// Fallback path kernels (round-1), used only if ws_size is too small.
// ---------------------------------------------------------------------------
__global__ __launch_bounds__(1024) void maxs2_kernel(const float* __restrict__ s2,
                                                     float* __restrict__ M) {
    __shared__ float red[1024];
    float m = -1e30f;
    for (int i = threadIdx.x; i < N_NODES; i += 1024) m = fmaxf(m, s2[i]);
    red[threadIdx.x] = m;
    __syncthreads();
    for (int s = 512; s; s >>= 1) {
        if (threadIdx.x < s) red[threadIdx.x] = fmaxf(red[threadIdx.x], red[threadIdx.x + s]);
        __syncthreads();
    }
    if (threadIdx.x == 0) M[0] = red[0];
}

__global__ __launch_bounds__(256) void aggregate_kernel(const float* __restrict__ h,
                                                        const float* __restrict__ s1,
                                                        const float* __restrict__ s2,
                                                        const float* __restrict__ Mptr,
                                                        float* __restrict__ out) {
    __shared__ float w_lds[32][33];
    __shared__ float s2t[32];
    __shared__ float s1_loc[32];
    __shared__ float m_loc[32];

    const int t  = threadIdx.x;
    const int i0 = blockIdx.x * 32;
    const float Mv = Mptr[0];

    if (t < 32) {
        const float s1v = s1[i0 + t];
        s1_loc[t] = s1v;
        const float x = s1v + Mv;
        m_loc[t] = (x >= 0.f) ? x : ALPHA * x;
    }
    __syncthreads();

    const int g  = t >> 6;
    const int fl = t & 63;
    const int f4 = fl * 4;

    float acc[8][4] = {};
    float zacc[8]   = {};

    for (int j0 = 0; j0 < N_NODES; j0 += 32) {
        __syncthreads();
        if (t < 32) s2t[t] = s2[j0 + t];
        __syncthreads();
        #pragma unroll
        for (int q = 0; q < 4; ++q) {
            const int idx = t + q * 256;
            const int il  = idx >> 5;
            const int jl  = idx & 31;
            float e = s1_loc[il] + s2t[jl];
            e = (e >= 0.f) ? e : ALPHA * e;
            w_lds[il][jl] = __expf(e - m_loc[il]);
        }
        __syncthreads();

        #pragma unroll 4
        for (int jl = 0; jl < 32; ++jl) {
            const float4 hv = *(const float4*)(h + (size_t)(j0 + jl) * F_OUT + f4);
            #pragma unroll
            for (int r = 0; r < 8; ++r) {
                const float w = w_lds[g * 8 + r][jl];
                acc[r][0] += w * hv.x;
                acc[r][1] += w * hv.y;
                acc[r][2] += w * hv.z;
                acc[r][3] += w * hv.w;
                zacc[r]   += w;
            }
        }
    }

    #pragma unroll
    for (int r = 0; r < 8; ++r) {
        const int i = i0 + g * 8 + r;
        const float inv = 1.0f / zacc[r];
        float4 o;
        o.x = acc[r][0] * inv; o.y = acc[r][1] * inv;
        o.z = acc[r][2] * inv; o.w = acc[r][3] * inv;
        o.x = (o.x > 0.f) ? o.x : expm1f(o.x);
        o.y = (o.y > 0.f) ? o.y : expm1f(o.y);
        o.z = (o.z > 0.f) ? o.z : expm1f(o.z);
        o.w = (o.w > 0.f) ? o.w : expm1f(o.w);
        *(float4*)(out + (size_t)i * F_OUT + f4) = o;
    }
}

// ---------------------------------------------------------------------------
extern "C" void kernel_launch(void* const* d_in, const int* in_sizes, int n_in,
                              void* d_out, int out_size, void* d_ws, size_t ws_size,
                              hipStream_t stream) {
    const float* x = (const float*)d_in[0];   // [8192,512]
    const float* W = (const float*)d_in[1];   // [512,256]
    const float* a = (const float*)d_in[2];   // [512,1]
    float* out = (float*)d_out;               // [8192,256]

    // workspace layout (bytes)
    constexpr size_t SZ_H    = (size_t)N_NODES * F_OUT * 4;        // 8 MB
    constexpr size_t SZ_VEC  = (size_t)N_NODES * 4;                // 32 KB
    constexpr size_t SZ_CHNK = (size_t)NCHUNK * F_OUT * 4;         // 256 KB
    constexpr size_t SZ_CZ   = (size_t)NCHUNK * 4;                 // 1 KB

    constexpr size_t OFF_H     = 0;
    constexpr size_t OFF_S1    = OFF_H + SZ_H;
    constexpr size_t OFF_S2    = OFF_S1 + SZ_VEC;
    constexpr size_t OFF_V0    = OFF_S2 + SZ_VEC;
    constexpr size_t OFF_P0    = OFF_V0 + SZ_VEC;
    constexpr size_t OFF_V1    = OFF_P0 + SZ_VEC;
    constexpr size_t OFF_P1    = OFF_V1 + SZ_VEC;
    constexpr size_t OFF_CZN   = OFF_P1 + SZ_VEC;
    constexpr size_t OFF_CZP   = OFF_CZN + SZ_CZ;
    constexpr size_t OFF_CNEG  = OFF_CZP + SZ_CZ;
    constexpr size_t OFF_CPOS  = OFF_CNEG + SZ_CHNK;
    constexpr size_t REQUIRED  = OFF_CPOS + SZ_CHNK;               // ~8.8 MB

    char* ws = (char*)d_ws;
    float* h  = (float*)(ws + OFF_H);
    float* s1 = (float*)(ws + OFF_S1);
    float* s2 = (float*)(ws + OFF_S2);

    gemm_h<<<dim3(F_OUT / 64, N_NODES / 64), 256, 0, stream>>>(x, W, h);
    s12_kernel<<<N_NODES / 4, 256, 0, stream>>>(h, a, s1, s2);

    if (ws_size >= REQUIRED) {
        float* v0    = (float*)(ws + OFF_V0);
        int*   p0    = (int*)(ws + OFF_P0);
        float* v1    = (float*)(ws + OFF_V1);
        int*   p1    = (int*)(ws + OFF_P1);
        float* czn   = (float*)(ws + OFF_CZN);
        float* czp   = (float*)(ws + OFF_CZP);
        float* cneg  = (float*)(ws + OFF_CNEG);
        float* cpos  = (float*)(ws + OFF_CPOS);

        // parallel sort: 8 LDS segment sorts, then 3 rank-merge passes
        // v0 -> v1 (L=1024) -> v0 (L=2048) -> v1 (L=4096); final in v1/p1
        seg_sort<<<N_NODES / SEG, SEG, 0, stream>>>(s2, v0, p0);
        merge_pass<<<N_NODES / 256, 256, 0, stream>>>(v0, p0, v1, p1, 1024);
        merge_pass<<<N_NODES / 256, 256, 0, stream>>>(v1, p1, v0, p0, 2048);
        merge_pass<<<N_NODES / 256, 256, 0, stream>>>(v0, p0, v1, p1, 4096);

        chunk_sums<<<NCHUNK, 256, 0, stream>>>(h, v1, p1, cneg, cpos, czn, czp);
        scan_chunks<<<1, 256, 0, stream>>>(cneg, cpos, czn, czp);
        rows2_kernel<<<N_NODES / 4, 256, 0, stream>>>(s1, v1, p1, h,
                                                      cneg, cpos, czn, czp, out);
    } else {
        // fallback: round-1 flash-style path (needs only ~8.5 MB)
        float* M = (float*)(ws + OFF_V0);
        maxs2_kernel<<<1, 1024, 0, stream>>>(s2, M);
        aggregate_kernel<<<N_NODES / 32, 256, 0, stream>>>(h, s1, s2, M, out);
    }
}

// Round 9
// 163.978 us; speedup vs baseline: 1.2081x; 1.2081x over previous
//
#include <hip/hip_runtime.h>
#include <hip/hip_bf16.h>

#define N_NODES 8192
#define F_IN    512
#define F_OUT   256
#define ALPHA   0.2f
#define CHUNK   32
#define NCHUNK  (N_NODES / CHUNK)   // 256
#define SEG     1024                // seg_sort segment length
#define BM      128
#define BN      64
#define BK      16

// ---------------------------------------------------------------------------
// Kernel 1: h = x @ W   [8192,512] x [512,256] -> [8192,256], f32.
// BM=128 BN=64 BK=16, 512 threads, 4x4 micro-tile, reg-prefetch dbuf.
// Grid (4,64) = 256 blocks = 1 per CU, 8 waves/CU.
// ---------------------------------------------------------------------------
__global__ __launch_bounds__(512) void gemm_h(const float* __restrict__ A,
                                              const float* __restrict__ B,
                                              float* __restrict__ C) {
    __shared__ float As[BK][BM + 4];   // [16][132], stored transposed As[k][m]
    __shared__ float Bs[BK][BN + 4];   // [16][68]
    const int t  = threadIdx.x;
    const int m0 = blockIdx.y * BM;
    const int n0 = blockIdx.x * BN;

    const int ar = t >> 2;             // 0..127  A row within tile
    const int ak = (t & 3) * 4;        // 0,4,8,12 k-offset
    const int br = t >> 4;             // 0..15 (t<256) B k-row
    const int bc = (t & 15) * 4;       // 0..60  B col

    const int ty = t >> 4;             // 0..31 -> output rows ty*4..+3
    const int tx = t & 15;             // 0..15 -> output cols tx*4..+3

    // prefetch first tile into registers
    float4 aReg = *(const float4*)(A + (size_t)(m0 + ar) * F_IN + ak);
    float4 bReg = make_float4(0.f, 0.f, 0.f, 0.f);
    if (t < 256) bReg = *(const float4*)(B + (size_t)br * F_OUT + n0 + bc);

    float acc[4][4] = {};

    for (int k0 = 0; k0 < F_IN; k0 += BK) {
        __syncthreads();               // LDS free to overwrite
        As[ak + 0][ar] = aReg.x;
        As[ak + 1][ar] = aReg.y;
        As[ak + 2][ar] = aReg.z;
        As[ak + 3][ar] = aReg.w;
        if (t < 256) *(float4*)(&Bs[br][bc]) = bReg;
        __syncthreads();
        if (k0 + BK < F_IN) {          // issue next-tile loads; consumed next iter
            aReg = *(const float4*)(A + (size_t)(m0 + ar) * F_IN + k0 + BK + ak);
            if (t < 256) bReg = *(const float4*)(B + (size_t)(k0 + BK + br) * F_OUT + n0 + bc);
        }
        #pragma unroll
        for (int k = 0; k < BK; ++k) {
            const float4 a4 = *(const float4*)(&As[k][ty * 4]);
            const float4 b4 = *(const float4*)(&Bs[k][tx * 4]);
            acc[0][0] += a4.x * b4.x; acc[0][1] += a4.x * b4.y;
            acc[0][2] += a4.x * b4.z; acc[0][3] += a4.x * b4.w;
            acc[1][0] += a4.y * b4.x; acc[1][1] += a4.y * b4.y;
            acc[1][2] += a4.y * b4.z; acc[1][3] += a4.y * b4.w;
            acc[2][0] += a4.z * b4.x; acc[2][1] += a4.z * b4.y;
            acc[2][2] += a4.z * b4.z; acc[2][3] += a4.z * b4.w;
            acc[3][0] += a4.w * b4.x; acc[3][1] += a4.w * b4.y;
            acc[3][2] += a4.w * b4.z; acc[3][3] += a4.w * b4.w;
        }
    }
    #pragma unroll
    for (int r = 0; r < 4; ++r) {
        float4 o = make_float4(acc[r][0], acc[r][1], acc[r][2], acc[r][3]);
        *(float4*)(C + (size_t)(m0 + ty * 4 + r) * F_OUT + n0 + tx * 4) = o;
    }
}

// ---------------------------------------------------------------------------
// Kernel 2: s1[i] = h[i,:].a[0:256],  s2[i] = h[i,:].a[256:512]
// ---------------------------------------------------------------------------
__global__ __launch_bounds__(256) void s12_kernel(const float* __restrict__ h,
                                                  const float* __restrict__ a,
                                                  float* __restrict__ s1,
                                                  float* __restrict__ s2) {
    const int wave = threadIdx.x >> 6;
    const int lane = threadIdx.x & 63;
    const int row  = blockIdx.x * 4 + wave;

    const float4 hv = *(const float4*)(h + (size_t)row * F_OUT + lane * 4);
    const float4 a1 = *(const float4*)(a + lane * 4);
    const float4 a2 = *(const float4*)(a + F_OUT + lane * 4);

    float p1 = hv.x * a1.x + hv.y * a1.y + hv.z * a1.z + hv.w * a1.w;
    float p2 = hv.x * a2.x + hv.y * a2.y + hv.z * a2.z + hv.w * a2.w;
    #pragma unroll
    for (int off = 32; off; off >>= 1) {
        p1 += __shfl_xor(p1, off);
        p2 += __shfl_xor(p2, off);
    }
    if (lane == 0) { s1[row] = p1; s2[row] = p2; }
}

// ---------------------------------------------------------------------------
// Kernel 3a: sort 8 segments of 1024 (val,idx) pairs, each block in LDS.
// ---------------------------------------------------------------------------
__global__ __launch_bounds__(1024) void seg_sort(const float* __restrict__ s2,
                                                 float* __restrict__ v,
                                                 int* __restrict__ p) {
    __shared__ float sv[SEG];
    __shared__ int   sp[SEG];
    const int t    = threadIdx.x;
    const int base = blockIdx.x * SEG;
    sv[t] = s2[base + t];
    sp[t] = base + t;
    __syncthreads();
    for (int k = 2; k <= SEG; k <<= 1) {
        for (int j = k >> 1; j > 0; j >>= 1) {
            const int ixj = t ^ j;
            if (ixj > t) {
                const bool up = ((t & k) == 0);
                const float av = sv[t], bv = sv[ixj];
                if (up ? (av > bv) : (av < bv)) {
                    sv[t] = bv; sv[ixj] = av;
                    const int pa = sp[t]; sp[t] = sp[ixj]; sp[ixj] = pa;
                }
            }
            __syncthreads();
        }
    }
    v[base + t] = sv[t];
    p[base + t] = sp[t];
}

// ---------------------------------------------------------------------------
// Kernel 3b: parallel merge of adjacent sorted runs of length L into 2L.
// ---------------------------------------------------------------------------
__global__ __launch_bounds__(256) void merge_pass(const float* __restrict__ vin,
                                                  const int* __restrict__ pin,
                                                  float* __restrict__ vout,
                                                  int* __restrict__ pout,
                                                  int L) {
    const int gid   = blockIdx.x * 256 + threadIdx.x;   // 0..8191
    const int pair  = gid / (2 * L);
    const int local = gid - pair * 2 * L;
    const int beg   = pair * 2 * L;

    if (local < L) {                       // element of run A
        const int i     = local;
        const float key = vin[beg + i];
        const int  idx  = pin[beg + i];
        const float* Brun = vin + beg + L;
        int lo = 0, hi = L;
        while (lo < hi) {                  // lower_bound: # of B < key
            const int mid = (lo + hi) >> 1;
            if (Brun[mid] < key) lo = mid + 1; else hi = mid;
        }
        vout[beg + i + lo] = key;
        pout[beg + i + lo] = idx;
    } else {                               // element of run B
        const int i     = local - L;
        const float key = vin[beg + L + i];
        const int  idx  = pin[beg + L + i];
        const float* Arun = vin + beg;
        int lo = 0, hi = L;
        while (lo < hi) {                  // upper_bound: # of A <= key
            const int mid = (lo + hi) >> 1;
            if (Arun[mid] <= key) lo = mid + 1; else hi = mid;
        }
        vout[beg + lo + i] = key;
        pout[beg + lo + i] = idx;
    }
}

// ---------------------------------------------------------------------------
// Kernel 4: per-chunk TOTALS: cneg[c][f], cpos[c][f], czn/czp scalars.
// ---------------------------------------------------------------------------
__global__ __launch_bounds__(256) void chunk_sums(const float* __restrict__ h,
                                                  const float* __restrict__ v,
                                                  const int* __restrict__ p,
                                                  float* __restrict__ cneg,
                                                  float* __restrict__ cpos,
                                                  float* __restrict__ czn,
                                                  float* __restrict__ czp) {
    const int c = blockIdx.x;
    const int f = threadIdx.x;
    const float M = v[N_NODES - 1];
    float accN = 0.f, accP = 0.f, zn = 0.f, zp = 0.f;
    #pragma unroll 8
    for (int tt = 0; tt < CHUNK; ++tt) {
        const int j = c * CHUNK + tt;
        const float vj = v[j];
        const int pj   = p[j];
        const float wn = __expf(ALPHA * vj);
        const float wp = __expf(vj - M);
        const float hv = h[(size_t)pj * F_OUT + f];
        accN += wn * hv; accP += wp * hv;
        zn += wn; zp += wp;
    }
    cneg[c * F_OUT + f] = accN;
    cpos[c * F_OUT + f] = accP;
    if (f == 0) { czn[c] = zn; czp[c] = zp; }
}

// ---------------------------------------------------------------------------
// Kernel 5: exclusive scans of chunk totals, PARALLEL over features.
// Block f (256 blocks): Hillis-Steele over the 256 chunks of feature f.
// cneg[c][f] <- sum chunks < c ; cpos[c][f] <- sum chunks > c.
// Block 0 additionally scans the scalar czn (prefix) / czp (suffix).
// ---------------------------------------------------------------------------
__global__ __launch_bounds__(256) void scan_cols(float* __restrict__ cneg,
                                                 float* __restrict__ cpos,
                                                 float* __restrict__ czn,
                                                 float* __restrict__ czp) {
    const int f = blockIdx.x;    // feature column
    const int c = threadIdx.x;   // chunk
    __shared__ float bn[NCHUNK];
    __shared__ float bp[NCHUNK];

    const float xn = cneg[(size_t)c * F_OUT + f];
    const float xp = cpos[(size_t)c * F_OUT + f];
    bn[c] = xn; bp[c] = xp;
    __syncthreads();
    #pragma unroll
    for (int off = 1; off < NCHUNK; off <<= 1) {
        const float an = (c >= off) ? bn[c - off] : 0.f;           // prefix
        const float ap = (c + off < NCHUNK) ? bp[c + off] : 0.f;   // suffix
        __syncthreads();
        bn[c] += an; bp[c] += ap;
        __syncthreads();
    }
    cneg[(size_t)c * F_OUT + f] = bn[c] - xn;   // exclusive prefix
    cpos[(size_t)c * F_OUT + f] = bp[c] - xp;   // exclusive suffix

    if (blockIdx.x == 0) {   // block-uniform: scalar scans
        __shared__ float sn[NCHUNK];
        __shared__ float sp_[NCHUNK];
        const float yn = czn[c];
        const float yp = czp[c];
        sn[c] = yn; sp_[c] = yp;
        __syncthreads();
        #pragma unroll
        for (int off = 1; off < NCHUNK; off <<= 1) {
            const float an = (c >= off) ? sn[c - off] : 0.f;
            const float ap = (c + off < NCHUNK) ? sp_[c + off] : 0.f;
            __syncthreads();
            sn[c] += an; sp_[c] += ap;
            __syncthreads();
        }
        czn[c] = sn[c] - yn;
        czp[c] = sp_[c] - yp;
    }
}

// ---------------------------------------------------------------------------
// Kernel 6: per-row output, fused tail.
// ---------------------------------------------------------------------------
__global__ __launch_bounds__(256) void rows2_kernel(const float* __restrict__ s1,
                                                    const float* __restrict__ v,
                                                    const int* __restrict__ p,
                                                    const float* __restrict__ h,
                                                    const float* __restrict__ cnegS,
                                                    const float* __restrict__ cposS,
                                                    const float* __restrict__ cznS,
                                                    const float* __restrict__ czpS,
                                                    float* __restrict__ out) {
    const int wave = threadIdx.x >> 6;
    const int lane = threadIdx.x & 63;
    const int i = blockIdx.x * 4 + wave;

    const float s1v = s1[i];
    const float M   = v[N_NODES - 1];

    // lower_bound: first k with v[k] >= -s1v
    const float thr = -s1v;
    int lo = 0, hi = N_NODES;
    while (lo < hi) {
        const int mid = (lo + hi) >> 1;
        if (v[mid] < thr) lo = mid + 1; else hi = mid;
    }
    const int k = lo;
    const int c = min(k >> 5, NCHUNK - 1);
    const int start = c * CHUNK;

    const float4 bN = *(const float4*)(cnegS + (size_t)c * F_OUT + lane * 4);
    const float4 bP = *(const float4*)(cposS + (size_t)c * F_OUT + lane * 4);
    float aN0 = bN.x, aN1 = bN.y, aN2 = bN.z, aN3 = bN.w;
    float aP0 = bP.x, aP1 = bP.y, aP2 = bP.z, aP3 = bP.w;
    float zn = cznS[c];
    float zp = czpS[c];

    #pragma unroll 8
    for (int tt = 0; tt < CHUNK; ++tt) {
        const int j = start + tt;
        const float vj = v[j];
        const int pj   = p[j];
        const float4 hv = *(const float4*)(h + (size_t)pj * F_OUT + lane * 4);
        if (j < k) {
            const float wn = __expf(ALPHA * vj);
            aN0 += wn * hv.x; aN1 += wn * hv.y; aN2 += wn * hv.z; aN3 += wn * hv.w;
            zn += wn;
        } else {
            const float wp = __expf(vj - M);
            aP0 += wp * hv.x; aP1 += wp * hv.y; aP2 += wp * hv.z; aP3 += wp * hv.w;
            zp += wp;
        }
    }

    const float x  = s1v + M;
    const float m  = (x >= 0.f) ? x : ALPHA * x;
    const float cp = __expf(x - m);
    const float cn = __expf(ALPHA * s1v - m);

    const float invZ = 1.0f / (cp * zp + cn * zn);

    float4 o;
    o.x = (cp * aP0 + cn * aN0) * invZ;
    o.y = (cp * aP1 + cn * aN1) * invZ;
    o.z = (cp * aP2 + cn * aN2) * invZ;
    o.w = (cp * aP3 + cn * aN3) * invZ;
    o.x = (o.x > 0.f) ? o.x : expm1f(o.x);
    o.y = (o.y > 0.f) ? o.y : expm1f(o.y);
    o.z = (o.z > 0.f) ? o.z : expm1f(o.z);
    o.w = (o.w > 0.f) ? o.w : expm1f(o.w);
    *(float4*)(out + (size_t)i * F_OUT + lane * 4) = o;
}

// ---------------------------------------------------------------------------
// Fallback path kernels (round-1), used only if ws_size is too small.
// ---------------------------------------------------------------------------
__global__ __launch_bounds__(1024) void maxs2_kernel(const float* __restrict__ s2,
                                                     float* __restrict__ M) {
    __shared__ float red[1024];
    float m = -1e30f;
    for (int i = threadIdx.x; i < N_NODES; i += 1024) m = fmaxf(m, s2[i]);
    red[threadIdx.x] = m;
    __syncthreads();
    for (int s = 512; s; s >>= 1) {
        if (threadIdx.x < s) red[threadIdx.x] = fmaxf(red[threadIdx.x], red[threadIdx.x + s]);
        __syncthreads();
    }
    if (threadIdx.x == 0) M[0] = red[0];
}

__global__ __launch_bounds__(256) void aggregate_kernel(const float* __restrict__ h,
                                                        const float* __restrict__ s1,
                                                        const float* __restrict__ s2,
                                                        const float* __restrict__ Mptr,
                                                        float* __restrict__ out) {
    __shared__ float w_lds[32][33];
    __shared__ float s2t[32];
    __shared__ float s1_loc[32];
    __shared__ float m_loc[32];

    const int t  = threadIdx.x;
    const int i0 = blockIdx.x * 32;
    const float Mv = Mptr[0];

    if (t < 32) {
        const float s1v = s1[i0 + t];
        s1_loc[t] = s1v;
        const float x = s1v + Mv;
        m_loc[t] = (x >= 0.f) ? x : ALPHA * x;
    }
    __syncthreads();

    const int g  = t >> 6;
    const int fl = t & 63;
    const int f4 = fl * 4;

    float acc[8][4] = {};
    float zacc[8]   = {};

    for (int j0 = 0; j0 < N_NODES; j0 += 32) {
        __syncthreads();
        if (t < 32) s2t[t] = s2[j0 + t];
        __syncthreads();
        #pragma unroll
        for (int q = 0; q < 4; ++q) {
            const int idx = t + q * 256;
            const int il  = idx >> 5;
            const int jl  = idx & 31;
            float e = s1_loc[il] + s2t[jl];
            e = (e >= 0.f) ? e : ALPHA * e;
            w_lds[il][jl] = __expf(e - m_loc[il]);
        }
        __syncthreads();

        #pragma unroll 4
        for (int jl = 0; jl < 32; ++jl) {
            const float4 hv = *(const float4*)(h + (size_t)(j0 + jl) * F_OUT + f4);
            #pragma unroll
            for (int r = 0; r < 8; ++r) {
                const float w = w_lds[g * 8 + r][jl];
                acc[r][0] += w * hv.x;
                acc[r][1] += w * hv.y;
                acc[r][2] += w * hv.z;
                acc[r][3] += w * hv.w;
                zacc[r]   += w;
            }
        }
    }

    #pragma unroll
    for (int r = 0; r < 8; ++r) {
        const int i = i0 + g * 8 + r;
        const float inv = 1.0f / zacc[r];
        float4 o;
        o.x = acc[r][0] * inv; o.y = acc[r][1] * inv;
        o.z = acc[r][2] * inv; o.w = acc[r][3] * inv;
        o.x = (o.x > 0.f) ? o.x : expm1f(o.x);
        o.y = (o.y > 0.f) ? o.y : expm1f(o.y);
        o.z = (o.z > 0.f) ? o.z : expm1f(o.z);
        o.w = (o.w > 0.f) ? o.w : expm1f(o.w);
        *(float4*)(out + (size_t)i * F_OUT + f4) = o;
    }
}

// ---------------------------------------------------------------------------
extern "C" void kernel_launch(void* const* d_in, const int* in_sizes, int n_in,
                              void* d_out, int out_size, void* d_ws, size_t ws_size,
                              hipStream_t stream) {
    const float* x = (const float*)d_in[0];   // [8192,512]
    const float* W = (const float*)d_in[1];   // [512,256]
    const float* a = (const float*)d_in[2];   // [512,1]
    float* out = (float*)d_out;               // [8192,256]

    // workspace layout (bytes)
    constexpr size_t SZ_H    = (size_t)N_NODES * F_OUT * 4;        // 8 MB
    constexpr size_t SZ_VEC  = (size_t)N_NODES * 4;                // 32 KB
    constexpr size_t SZ_CHNK = (size_t)NCHUNK * F_OUT * 4;         // 256 KB
    constexpr size_t SZ_CZ   = (size_t)NCHUNK * 4;                 // 1 KB

    constexpr size_t OFF_H     = 0;
    constexpr size_t OFF_S1    = OFF_H + SZ_H;
    constexpr size_t OFF_S2    = OFF_S1 + SZ_VEC;
    constexpr size_t OFF_V0    = OFF_S2 + SZ_VEC;
    constexpr size_t OFF_P0    = OFF_V0 + SZ_VEC;
    constexpr size_t OFF_V1    = OFF_P0 + SZ_VEC;
    constexpr size_t OFF_P1    = OFF_V1 + SZ_VEC;
    constexpr size_t OFF_CZN   = OFF_P1 + SZ_VEC;
    constexpr size_t OFF_CZP   = OFF_CZN + SZ_CZ;
    constexpr size_t OFF_CNEG  = OFF_CZP + SZ_CZ;
    constexpr size_t OFF_CPOS  = OFF_CNEG + SZ_CHNK;
    constexpr size_t REQUIRED  = OFF_CPOS + SZ_CHNK;               // ~8.8 MB

    char* ws = (char*)d_ws;
    float* h  = (float*)(ws + OFF_H);
    float* s1 = (float*)(ws + OFF_S1);
    float* s2 = (float*)(ws + OFF_S2);

    gemm_h<<<dim3(F_OUT / BN, N_NODES / BM), 512, 0, stream>>>(x, W, h);
    s12_kernel<<<N_NODES / 4, 256, 0, stream>>>(h, a, s1, s2);

    if (ws_size >= REQUIRED) {
        float* v0    = (float*)(ws + OFF_V0);
        int*   p0    = (int*)(ws + OFF_P0);
        float* v1    = (float*)(ws + OFF_V1);
        int*   p1    = (int*)(ws + OFF_P1);
        float* czn   = (float*)(ws + OFF_CZN);
        float* czp   = (float*)(ws + OFF_CZP);
        float* cneg  = (float*)(ws + OFF_CNEG);
        float* cpos  = (float*)(ws + OFF_CPOS);

        // parallel sort: 8 LDS segment sorts, then 3 rank-merge passes
        seg_sort<<<N_NODES / SEG, SEG, 0, stream>>>(s2, v0, p0);
        merge_pass<<<N_NODES / 256, 256, 0, stream>>>(v0, p0, v1, p1, 1024);
        merge_pass<<<N_NODES / 256, 256, 0, stream>>>(v1, p1, v0, p0, 2048);
        merge_pass<<<N_NODES / 256, 256, 0, stream>>>(v0, p0, v1, p1, 4096);

        chunk_sums<<<NCHUNK, 256, 0, stream>>>(h, v1, p1, cneg, cpos, czn, czp);
        scan_cols<<<F_OUT, NCHUNK, 0, stream>>>(cneg, cpos, czn, czp);
        rows2_kernel<<<N_NODES / 4, 256, 0, stream>>>(s1, v1, p1, h,
                                                      cneg, cpos, czn, czp, out);
    } else {
        // fallback: round-1 flash-style path
        float* M = (float*)(ws + OFF_V0);
        maxs2_kernel<<<1, 1024, 0, stream>>>(s2, M);
        aggregate_kernel<<<N_NODES / 32, 256, 0, stream>>>(h, s1, s2, M, out);
    }
}